// Round 4
// baseline (532.764 us; speedup 1.0000x reference)
//
#include <hip/hip_runtime.h>

// Problem constants (fixed by the reference's setup_inputs)
#define NB 2          // batch
#define NN 262144     // events per batch (2^18)
#define ND 10         // temporal bins (base)
#define NR 11         // warp references (base + 1)
#define HH 256
#define WW 256
#define HWSZ 65536
#define SROWS 4       // rows per y-strip
#define NSTRIP 64     // 256 / SROWS
#define PLANE (SROWS * WW)    // 1024 floats per (pol, e/t) plane
#define BINCAP (NN * 6)       // worst-case entries per pass (6 r's, one batch)
#define FILL_E 512            // events per fill block
#define EPSF 1e-9f

// ws layout (18.9 MB -- well under the 23.07 MB proven-good ceiling):
//   float bins[BINCAP*3] : per-(b-pass, r, strip) PAYLOAD lists: (wx, wy, ts|pol)
//                          12 B/entry, reused across 4 passes = (b) x (r-half)
//   uint  counts[1408]   : [b][r][strip] exact pair counts (all passes, counted once)
//   float accum[64]      : (sumsq, inside) per (b,r)
//   uint  starts[4*512]  : per-pass exclusive bin offsets (+sentinel)
//   uint  cursors[4*512] : per-pass mutable fill reservation cursors
//
// R3 lesson (counters): scan = 134 us at VALUBusy 6%, VGPR 12 -- a serial
// dependent scatter chain (bins[i] -> rec[idx] -> tsq[idx]) sustaining only
// ~2.5 outstanding misses/wave. Fix: bins store the 12B PAYLOAD (wx, wy,
// ts|pol) computed at fill time with the bit-identical fmaf chain -> scan
// streams coalesced, zero gathers. 4 passes (b x r-half) keep ws at 18.9 MB;
// fill recomputes the warp from events+flow (deterministic -> counts exact).
// Straddlers: block s streams bin s-1 fully; row guards mask non-matches.

__device__ __forceinline__ unsigned strip_of(float ax, float ay, float dx, float dy, float rf)
{
    // strip of first in-range row, or 0xFF if no corner can land
    float wx = fmaf(rf, dx, ax);
    float wy = fmaf(rf, dy, ay);
    int xi = (int)floorf(wx);
    int yi = (int)floorf(wy);
    if (xi + 1 < 0 || xi >= WW || yi + 1 < 0 || yi >= HH) return 0xFFu;
    int rr = yi < 0 ? 0 : yi;
    return (unsigned)(rr >> 2);   // SROWS = 4
}

__device__ __forceinline__ void warp_of(const float* __restrict__ e,
                                        const float* __restrict__ flow, int b,
                                        float& ax, float& ay, float& dx, float& dy,
                                        float& tspol)
{
    float x  = e[0];
    float y  = e[1];
    float t  = e[2];
    float ts = e[3];
    float p  = e[4];

    int zi = (int)floorf(t);
    zi = zi < 0 ? 0 : (zi > ND - 1 ? ND - 1 : zi);
    int x0 = (int)floorf(x);
    x0 = x0 < 0 ? 0 : (x0 > WW - 2 ? WW - 2 : x0);
    int y0 = (int)floorf(y);
    y0 = y0 < 0 ? 0 : (y0 > HH - 2 ? HH - 2 : y0);
    float fx = fminf(fmaxf(x - (float)x0, 0.0f), 1.0f);
    float fy = fminf(fmaxf(y - (float)y0, 0.0f), 1.0f);

    const float2* f2 = (const float2*)flow + ((size_t)b * ND + zi) * HWSZ;
    float2 f00 = f2[y0 * WW + x0];
    float2 f01 = f2[y0 * WW + x0 + 1];
    float2 f10 = f2[(y0 + 1) * WW + x0];
    float2 f11 = f2[(y0 + 1) * WW + x0 + 1];
    float w00 = (1.0f - fx) * (1.0f - fy);
    float w01 = fx * (1.0f - fy);
    float w10 = (1.0f - fx) * fy;
    float w11 = fx * fy;
    dx = w00 * f00.x + w01 * f01.x + w10 * f10.x + w11 * f11.x;
    dy = w00 * f00.y + w01 * f01.y + w10 * f10.y + w11 * f11.y;
    ax = fmaf(-t, dx, x);
    ay = fmaf(-t, dy, y);

    int pi = (p != 0.0f) ? 1 : 0;
    tspol = __int_as_float(__float_as_int(ts) | (pi << 31));   // ts >= 0 always
}

__global__ __launch_bounds__(1024) void cm_count(
    const float* __restrict__ events,
    const float* __restrict__ flow,
    unsigned* __restrict__ counts)
{
    __shared__ unsigned hist[NR * NSTRIP];      // 704 counters, 2.8 KB
    for (int i = threadIdx.x; i < NR * NSTRIP; i += 1024) hist[i] = 0u;
    __syncthreads();

    int gid = blockIdx.x * 1024 + threadIdx.x;  // grid covers NB*NN exactly
    int b = gid >> 18;                          // uniform per block

    float ax, ay, dx, dy, tp;
    warp_of(events + (size_t)gid * 5, flow, b, ax, ay, dx, dy, tp);

    #pragma unroll
    for (int r = 0; r < NR; ++r) {
        unsigned s = strip_of(ax, ay, dx, dy, (float)r);
        if (s != 0xFFu) atomicAdd(&hist[r * NSTRIP + (int)s], 1u);
    }
    __syncthreads();
    for (int i = threadIdx.x; i < NR * NSTRIP; i += 1024) {
        unsigned c = hist[i];
        if (c) atomicAdd(&counts[b * (NR * NSTRIP) + i], c);
    }
}

// exclusive prefix per pass; starts immutable (+sentinel), cursors consumed by fill
__global__ __launch_bounds__(1024) void cm_prefix(
    const unsigned* __restrict__ counts,
    unsigned* __restrict__ starts,
    unsigned* __restrict__ cursors)
{
    __shared__ unsigned sa[1024];
    int tid = threadIdx.x;

    for (int p = 0; p < 4; ++p) {
        int b = p >> 1;
        int rbase = (p & 1) * 6;
        int nrh = (p & 1) ? 5 : 6;
        int nb = nrh * NSTRIP;

        unsigned v = 0;
        if (tid < nb)
            v = counts[b * (NR * NSTRIP) + (rbase + (tid >> 6)) * NSTRIP + (tid & 63)];
        sa[tid] = v;
        __syncthreads();
        for (int off = 1; off < 1024; off <<= 1) {
            unsigned x = sa[tid];
            if (tid >= off) x += sa[tid - off];
            __syncthreads();
            sa[tid] = x;
            __syncthreads();
        }
        if (tid < nb) {
            unsigned ex = tid ? sa[tid - 1] : 0u;
            starts[p * 512 + tid] = ex;
            cursors[p * 512 + tid] = ex;
        }
        if (tid == 0) starts[p * 512 + nb] = sa[nb - 1];
        __syncthreads();
    }
}

__global__ __launch_bounds__(512) void cm_fill(
    const float* __restrict__ events,
    const float* __restrict__ flow,
    float* __restrict__ bins,
    unsigned* __restrict__ cursors,
    int b, int rbase, int nrh)
{
    __shared__ unsigned char stash[FILL_E * 6];   // 3 KB
    __shared__ unsigned cnt[6 * NSTRIP];          // 384
    __shared__ unsigned base[6 * NSTRIP];

    int nbin = nrh * NSTRIP;
    for (int i = threadIdx.x; i < nbin; i += 512) cnt[i] = 0u;
    __syncthreads();

    int el = threadIdx.x;                          // one event per thread
    int gid = b * NN + blockIdx.x * FILL_E + el;

    float ax, ay, dx, dy, tp;
    warp_of(events + (size_t)gid * 5, flow, b, ax, ay, dx, dy, tp);

    for (int rl = 0; rl < nrh; ++rl) {
        unsigned s = strip_of(ax, ay, dx, dy, (float)(rbase + rl));
        stash[el * 6 + rl] = (unsigned char)s;
        if (s != 0xFFu) atomicAdd(&cnt[rl * NSTRIP + (int)s], 1u);
    }
    __syncthreads();
    for (int i = threadIdx.x; i < nbin; i += 512) {
        unsigned c = cnt[i];
        base[i] = c ? atomicAdd(&cursors[i], c) : 0u;
    }
    __syncthreads();
    for (int i = threadIdx.x; i < nbin; i += 512) cnt[i] = 0u;   // reuse as ranks
    __syncthreads();

    for (int rl = 0; rl < nrh; ++rl) {
        unsigned s = stash[el * 6 + rl];
        if (s != 0xFFu) {
            int bin = rl * NSTRIP + (int)s;
            unsigned rank = atomicAdd(&cnt[bin], 1u);
            size_t off = (size_t)(base[bin] + rank) * 3;
            float rf = (float)(rbase + rl);
            bins[off + 0] = fmaf(rf, dx, ax);   // wx -- bit-identical to scan chain
            bins[off + 1] = fmaf(rf, dy, ay);   // wy
            bins[off + 2] = tp;                 // ts with sign = polarity
        }
    }
}

__global__ __launch_bounds__(512) void cm_scan(
    const float* __restrict__ bins,
    const unsigned* __restrict__ starts,
    int b, int rbase,
    float* __restrict__ accum)
{
    __shared__ float acc[4 * PLANE];   // 16 KB: [pol][iwe|iwt][4*256]

    int blk = blockIdx.x;
    int rl = blk >> 6;
    int s  = blk & 63;
    int r  = rbase + rl;
    int ty0 = s * SROWS;

    for (int i = threadIdx.x; i < 4 * PLANE; i += 512) acc[i] = 0.0f;
    __syncthreads();

    auto process = [&](unsigned i) {
        size_t o = (size_t)i * 3;
        float wx  = bins[o + 0];
        float wy  = bins[o + 1];
        float tpv = bins[o + 2];
        int pi = (int)((unsigned)__float_as_int(tpv) >> 31);
        float tsv = fabsf(tpv);
        float fwx = floorf(wx);
        float fwy = floorf(wy);
        int xi = (int)fwx;
        int yi = (int)fwy;
        float axf = wx - fwx;
        float ayf = wy - fwy;
        float* ap = acc + pi * (2 * PLANE);
        float c00 = (1.0f - axf) * (1.0f - ayf);
        float c01 = axf * (1.0f - ayf);
        float c10 = (1.0f - axf) * ayf;
        float c11 = axf * ayf;
        #define CM_CORNER(XI, YI, WV)                                          \
            if ((XI) >= 0 && (XI) < WW && (YI) >= ty0 && (YI) < ty0 + SROWS) { \
                int liq = ((YI) - ty0) * WW + (XI);                            \
                atomicAdd(ap + liq,         (WV));                             \
                atomicAdd(ap + PLANE + liq, (WV) * tsv);                       \
            }
        CM_CORNER(xi,     yi,     c00)
        CM_CORNER(xi + 1, yi,     c01)
        CM_CORNER(xi,     yi + 1, c10)
        CM_CORNER(xi + 1, yi + 1, c11)
        #undef CM_CORNER
    };

    unsigned own_s = starts[blk], own_e = starts[blk + 1];
    for (unsigned i = own_s + threadIdx.x; i < own_e; i += 512) process(i);

    if (s > 0) {   // straddlers from strip s-1 land their yi+1 row here
        unsigned nb_s = starts[blk - 1];
        for (unsigned i = nb_s + threadIdx.x; i < own_s; i += 512) process(i);
    }
    __syncthreads();

    float ss = 0.0f, ins = 0.0f;
    for (int i = threadIdx.x; i < PLANE; i += 512) {
        float e0 = acc[i];
        float t0 = acc[PLANE + i];
        float e1 = acc[2 * PLANE + i];
        float t1 = acc[3 * PLANE + i];
        float a0 = t0 / (e0 + EPSF);
        float a1 = t1 / (e1 + EPSF);
        ss += a0 * a0 + a1 * a1;
        ins += ((e0 + e1) > 0.0f) ? 1.0f : 0.0f;
    }
    #pragma unroll
    for (int off = 32; off > 0; off >>= 1) {
        ss  += __shfl_down(ss, off, 64);
        ins += __shfl_down(ins, off, 64);
    }
    __syncthreads();
    int lane = threadIdx.x & 63;
    int wv = threadIdx.x >> 6;
    if (lane == 0) { acc[2 * wv] = ss; acc[2 * wv + 1] = ins; }
    __syncthreads();
    if (threadIdx.x == 0) {
        float tss = 0.0f, tin = 0.0f;
        #pragma unroll
        for (int w = 0; w < 8; ++w) { tss += acc[2 * w]; tin += acc[2 * w + 1]; }
        int br = b * NR + r;
        atomicAdd(&accum[br * 2],     tss);
        atomicAdd(&accum[br * 2 + 1], tin);
    }
}

__global__ void cm_final(const float* __restrict__ accum, float* __restrict__ out)
{
    int i = threadIdx.x;
    if (i < NB * NR) {
        out[i] = accum[i * 2] / (accum[i * 2 + 1] + EPSF);
    }
}

extern "C" void kernel_launch(void* const* d_in, const int* in_sizes, int n_in,
                              void* d_out, int out_size, void* d_ws, size_t ws_size,
                              hipStream_t stream) {
    const float* events = (const float*)d_in[0];
    const float* flow   = (const float*)d_in[1];

    char* ws = (char*)d_ws;
    size_t off = 0;
    float* bins = (float*)(ws + off);         off += (size_t)BINCAP * 3 * 4;   // 18,874,368
    unsigned* counts = (unsigned*)(ws + off); off += NB * NR * NSTRIP * 4;     // 5,632
    float* accum = (float*)(ws + off);        off += 256;                      // contiguous w/ counts
    unsigned* starts = (unsigned*)(ws + off); off += 4 * 512 * 4;              // 8,192
    unsigned* cursors = (unsigned*)(ws + off); off += 4 * 512 * 4;             // 8,192

    // zero counts + accum (contiguous 5,888 B)
    hipMemsetAsync(counts, 0, NB * NR * NSTRIP * 4 + 256, stream);

    cm_count<<<NB * NN / 1024, 1024, 0, stream>>>(events, flow, counts);

    cm_prefix<<<1, 1024, 0, stream>>>(counts, starts, cursors);

    #pragma unroll
    for (int p = 0; p < 4; ++p) {
        int b = p >> 1;
        int rbase = (p & 1) * 6;
        int nrh = (p & 1) ? 5 : 6;
        cm_fill<<<NN / FILL_E, 512, 0, stream>>>(events, flow, bins,
                                                 cursors + p * 512, b, rbase, nrh);
        cm_scan<<<nrh * NSTRIP, 512, 0, stream>>>(bins, starts + p * 512,
                                                  b, rbase, accum);
    }

    cm_final<<<1, 64, 0, stream>>>(accum, (float*)d_out);
}

// Round 5
// 461.983 us; speedup vs baseline: 1.1532x; 1.1532x over previous
//
#include <hip/hip_runtime.h>

// Problem constants (fixed by the reference's setup_inputs)
#define NB 2          // batch
#define NN 262144     // events per batch (2^18)
#define ND 10         // temporal bins (base)
#define NR 11         // warp references (base + 1)
#define HH 256
#define WW 256
#define HWSZ 65536
#define SROWS 4       // rows per y-strip
#define NSTRIP 64     // 256 / SROWS
#define PLANE (SROWS * WW)    // 1024 floats per (pol, e/t) plane
#define BINCAP (NN * 4)       // worst-case entries per pass (<= 4 r's)
#define NPASS 6               // (b) x (r-sets {0-3, 4-7, 8-10})
#define PSTRIDE 264           // starts/cursors stride per pass (max nb=256, +sentinel)
#define EPSF 1e-9f

// ws layout (23.087 MB == R3's proven-running 23.09 MB):
//   float  bins[BINCAP*3]  : per-(r-local, strip) PAYLOAD (wx, wy, ts|pol), reused x6 passes
//   float4 rec[NB*NN]      : (ax, ay, dx, dy)  warp at ref r = (ax+r*dx, ay+r*dy)
//   float  tspol[NB*NN]    : ts with sign bit = polarity (ts >= 0 always)
//   uint   counts[1408]    : [b][r][strip] exact pair counts
//   float  accum[64]       : (sumsq, inside) per (b,r)
//   uint   starts/cursors[6*264]
//
// R4 lesson (counters): scan = 88 us/pass at VALUBusy 3.7%, occ 22%, VGPR 12.
// Serial chain: per trip, loads -> vmcnt(0) -> process -> loop (MLP=1); max-bin
// tail block runs ~22 trips x ~4K cyc while everyone idles. Fix: (1) batch 4
// entries with hoisted loads (12 dwords in flight), (2) merge own+neighbor bins
// into one contiguous stream (adjacent in memory; row guards mask), (3) fill
// reads rec (no flow re-gather), 6 passes of <=4 r's keep ws at 23.09 MB.

__device__ __forceinline__ unsigned strip_of(float ax, float ay, float dx, float dy, float rf)
{
    // strip of first in-range row, or 0xFF if no corner can land
    float wx = fmaf(rf, dx, ax);
    float wy = fmaf(rf, dy, ay);
    int xi = (int)floorf(wx);
    int yi = (int)floorf(wy);
    if (xi + 1 < 0 || xi >= WW || yi + 1 < 0 || yi >= HH) return 0xFFu;
    int rr = yi < 0 ? 0 : yi;
    return (unsigned)(rr >> 2);   // SROWS = 4
}

__global__ __launch_bounds__(1024) void cm_prep(
    const float* __restrict__ events,
    const float* __restrict__ flow,
    float4* __restrict__ rec,
    float* __restrict__ tspol,
    unsigned* __restrict__ counts)
{
    __shared__ unsigned hist[NR * NSTRIP];      // 704 counters, 2.8 KB
    for (int i = threadIdx.x; i < NR * NSTRIP; i += 1024) hist[i] = 0u;
    __syncthreads();

    int gid = blockIdx.x * 1024 + threadIdx.x;  // grid covers NB*NN exactly
    int b = gid >> 18;                          // uniform per block (256 blocks/batch)

    const float* e = events + (size_t)gid * 5;
    float x  = e[0];
    float y  = e[1];
    float t  = e[2];
    float ts = e[3];
    float p  = e[4];

    int zi = (int)floorf(t);
    zi = zi < 0 ? 0 : (zi > ND - 1 ? ND - 1 : zi);
    int x0 = (int)floorf(x);
    x0 = x0 < 0 ? 0 : (x0 > WW - 2 ? WW - 2 : x0);
    int y0 = (int)floorf(y);
    y0 = y0 < 0 ? 0 : (y0 > HH - 2 ? HH - 2 : y0);
    float fx = fminf(fmaxf(x - (float)x0, 0.0f), 1.0f);
    float fy = fminf(fmaxf(y - (float)y0, 0.0f), 1.0f);

    const float2* f2 = (const float2*)flow + ((size_t)b * ND + zi) * HWSZ;
    float2 f00 = f2[y0 * WW + x0];
    float2 f01 = f2[y0 * WW + x0 + 1];
    float2 f10 = f2[(y0 + 1) * WW + x0];
    float2 f11 = f2[(y0 + 1) * WW + x0 + 1];
    float w00 = (1.0f - fx) * (1.0f - fy);
    float w01 = fx * (1.0f - fy);
    float w10 = (1.0f - fx) * fy;
    float w11 = fx * fy;
    float dx = w00 * f00.x + w01 * f01.x + w10 * f10.x + w11 * f11.x;
    float dy = w00 * f00.y + w01 * f01.y + w10 * f10.y + w11 * f11.y;
    float ax = fmaf(-t, dx, x);
    float ay = fmaf(-t, dy, y);

    rec[gid] = make_float4(ax, ay, dx, dy);
    int pi = (p != 0.0f) ? 1 : 0;
    tspol[gid] = __int_as_float(__float_as_int(ts) | (pi << 31));   // ts >= 0

    #pragma unroll
    for (int r = 0; r < NR; ++r) {
        unsigned s = strip_of(ax, ay, dx, dy, (float)r);
        if (s != 0xFFu) atomicAdd(&hist[r * NSTRIP + (int)s], 1u);
    }
    __syncthreads();
    for (int i = threadIdx.x; i < NR * NSTRIP; i += 1024) {
        unsigned c = hist[i];
        if (c) atomicAdd(&counts[b * (NR * NSTRIP) + i], c);
    }
}

// exclusive prefix per pass; starts immutable (+sentinel), cursors consumed by fill
__global__ __launch_bounds__(256) void cm_prefix(
    const unsigned* __restrict__ counts,
    unsigned* __restrict__ starts,
    unsigned* __restrict__ cursors)
{
    __shared__ unsigned sa[256];
    int tid = threadIdx.x;

    for (int p = 0; p < NPASS; ++p) {
        int b = p / 3;
        int pr = p % 3;
        int rbase = pr * 4;                         // {0,4,8}
        int nrh = (pr == 2) ? 3 : 4;
        int nb = nrh * NSTRIP;                      // 256 or 192

        unsigned v = 0;
        if (tid < nb)
            v = counts[b * (NR * NSTRIP) + (rbase + (tid >> 6)) * NSTRIP + (tid & 63)];
        sa[tid] = v;
        __syncthreads();
        for (int off = 1; off < 256; off <<= 1) {
            unsigned x = sa[tid];
            if (tid >= off) x += sa[tid - off];
            __syncthreads();
            sa[tid] = x;
            __syncthreads();
        }
        if (tid < nb) {
            unsigned ex = tid ? sa[tid - 1] : 0u;
            starts[p * PSTRIDE + tid] = ex;
            cursors[p * PSTRIDE + tid] = ex;
        }
        if (tid == 0) starts[p * PSTRIDE + nb] = sa[nb - 1];
        __syncthreads();
    }
}

__global__ __launch_bounds__(512) void cm_fill(
    const float4* __restrict__ rec,
    const float* __restrict__ tspol,
    float* __restrict__ bins,
    unsigned* __restrict__ cursors,
    int b, int rbase, int nrh)
{
    __shared__ unsigned char stash[1024 * 4];     // 4 KB (2 events/thread x <=4 r)
    __shared__ unsigned cnt[4 * NSTRIP];          // 256
    __shared__ unsigned base[4 * NSTRIP];

    int nbin = nrh * NSTRIP;
    for (int i = threadIdx.x; i < nbin; i += 512) cnt[i] = 0u;
    __syncthreads();

    int e0 = blockIdx.x * 1024;
    const float4* rb = rec + (size_t)b * NN;
    const float*  tb = tspol + (size_t)b * NN;

    float4 ea[2];
    float tp[2];
    #pragma unroll
    for (int k = 0; k < 2; ++k) {
        int el = e0 + k * 512 + threadIdx.x;
        ea[k] = rb[el];
        tp[k] = tb[el];
    }

    #pragma unroll
    for (int k = 0; k < 2; ++k) {
        int sl = (k * 512 + threadIdx.x) * 4;
        for (int rl = 0; rl < nrh; ++rl) {
            unsigned s = strip_of(ea[k].x, ea[k].y, ea[k].z, ea[k].w, (float)(rbase + rl));
            stash[sl + rl] = (unsigned char)s;
            if (s != 0xFFu) atomicAdd(&cnt[rl * NSTRIP + (int)s], 1u);
        }
    }
    __syncthreads();
    for (int i = threadIdx.x; i < nbin; i += 512) {
        unsigned c = cnt[i];
        base[i] = c ? atomicAdd(&cursors[i], c) : 0u;
    }
    __syncthreads();
    for (int i = threadIdx.x; i < nbin; i += 512) cnt[i] = 0u;   // reuse as ranks
    __syncthreads();

    #pragma unroll
    for (int k = 0; k < 2; ++k) {
        int sl = (k * 512 + threadIdx.x) * 4;
        for (int rl = 0; rl < nrh; ++rl) {
            unsigned s = stash[sl + rl];
            if (s != 0xFFu) {
                int bin = rl * NSTRIP + (int)s;
                unsigned rank = atomicAdd(&cnt[bin], 1u);
                size_t o = (size_t)(base[bin] + rank) * 3;
                float rf = (float)(rbase + rl);
                bins[o + 0] = fmaf(rf, ea[k].z, ea[k].x);   // wx (bit-identical chain)
                bins[o + 1] = fmaf(rf, ea[k].w, ea[k].y);   // wy
                bins[o + 2] = tp[k];                        // ts with sign = polarity
            }
        }
    }
}

__global__ __launch_bounds__(512) void cm_scan(
    const float* __restrict__ bins,
    const unsigned* __restrict__ starts,
    int b, int rbase,
    float* __restrict__ accum)
{
    __shared__ float acc[4 * PLANE];   // 16 KB: [pol][iwe|iwt][4*256]

    int blk = blockIdx.x;
    int rl = blk >> 6;
    int s  = blk & 63;
    int r  = rbase + rl;
    int ty0 = s * SROWS;

    for (int i = threadIdx.x; i < 4 * PLANE; i += 512) acc[i] = 0.0f;
    __syncthreads();

    // merged contiguous stream: neighbor bin (strip s-1, same r) + own bin.
    // row guards mask non-matching rows; s=0 has no same-r neighbor.
    unsigned lo = (s > 0) ? starts[blk - 1] : starts[blk];
    unsigned hi = starts[blk + 1];

    for (unsigned bse = lo; bse < hi; bse += 2048) {
        float wx[4], wy[4], tv[4];
        bool val[4];
        #pragma unroll
        for (int k = 0; k < 4; ++k) {           // hoisted: 12 loads in flight
            unsigned i = bse + (unsigned)(k * 512) + threadIdx.x;
            bool v = i < hi;
            unsigned j = v ? i : (hi - 1);      // loop entered only if lo < hi
            size_t o = (size_t)j * 3;
            wx[k] = bins[o + 0];
            wy[k] = bins[o + 1];
            tv[k] = bins[o + 2];
            val[k] = v;
        }
        #pragma unroll
        for (int k = 0; k < 4; ++k) {
            if (!val[k]) continue;
            float wxk = wx[k], wyk = wy[k], tpv = tv[k];
            int pi = (int)((unsigned)__float_as_int(tpv) >> 31);
            float tsv = fabsf(tpv);
            float fwx = floorf(wxk);
            float fwy = floorf(wyk);
            int xi = (int)fwx;
            int yi = (int)fwy;
            float axf = wxk - fwx;
            float ayf = wyk - fwy;
            float* ap = acc + pi * (2 * PLANE);
            float c00 = (1.0f - axf) * (1.0f - ayf);
            float c01 = axf * (1.0f - ayf);
            float c10 = (1.0f - axf) * ayf;
            float c11 = axf * ayf;
            #define CM_CORNER(XI, YI, WV)                                          \
                if ((XI) >= 0 && (XI) < WW && (YI) >= ty0 && (YI) < ty0 + SROWS) { \
                    int liq = ((YI) - ty0) * WW + (XI);                            \
                    atomicAdd(ap + liq,         (WV));                             \
                    atomicAdd(ap + PLANE + liq, (WV) * tsv);                       \
                }
            CM_CORNER(xi,     yi,     c00)
            CM_CORNER(xi + 1, yi,     c01)
            CM_CORNER(xi,     yi + 1, c10)
            CM_CORNER(xi + 1, yi + 1, c11)
            #undef CM_CORNER
        }
    }
    __syncthreads();

    float ss = 0.0f, ins = 0.0f;
    for (int i = threadIdx.x; i < PLANE; i += 512) {
        float e0 = acc[i];
        float t0 = acc[PLANE + i];
        float e1 = acc[2 * PLANE + i];
        float t1 = acc[3 * PLANE + i];
        float a0 = t0 / (e0 + EPSF);
        float a1 = t1 / (e1 + EPSF);
        ss += a0 * a0 + a1 * a1;
        ins += ((e0 + e1) > 0.0f) ? 1.0f : 0.0f;
    }
    #pragma unroll
    for (int off = 32; off > 0; off >>= 1) {
        ss  += __shfl_down(ss, off, 64);
        ins += __shfl_down(ins, off, 64);
    }
    __syncthreads();
    int lane = threadIdx.x & 63;
    int wv = threadIdx.x >> 6;
    if (lane == 0) { acc[2 * wv] = ss; acc[2 * wv + 1] = ins; }
    __syncthreads();
    if (threadIdx.x == 0) {
        float tss = 0.0f, tin = 0.0f;
        #pragma unroll
        for (int w = 0; w < 8; ++w) { tss += acc[2 * w]; tin += acc[2 * w + 1]; }
        int br = b * NR + r;
        atomicAdd(&accum[br * 2],     tss);
        atomicAdd(&accum[br * 2 + 1], tin);
    }
}

__global__ void cm_final(const float* __restrict__ accum, float* __restrict__ out)
{
    int i = threadIdx.x;
    if (i < NB * NR) {
        out[i] = accum[i * 2] / (accum[i * 2 + 1] + EPSF);
    }
}

extern "C" void kernel_launch(void* const* d_in, const int* in_sizes, int n_in,
                              void* d_out, int out_size, void* d_ws, size_t ws_size,
                              hipStream_t stream) {
    const float* events = (const float*)d_in[0];
    const float* flow   = (const float*)d_in[1];

    char* ws = (char*)d_ws;
    size_t off = 0;
    float* bins = (float*)(ws + off);          off += (size_t)BINCAP * 3 * 4;        // 12,582,912
    float4* rec = (float4*)(ws + off);         off += (size_t)NB * NN * sizeof(float4); // 8,388,608
    float* tspol = (float*)(ws + off);         off += (size_t)NB * NN * sizeof(float);  // 2,097,152
    unsigned* counts = (unsigned*)(ws + off);  off += NB * NR * NSTRIP * 4;           // 5,632
    float* accum = (float*)(ws + off);         off += 256;                            // contiguous w/ counts
    unsigned* starts = (unsigned*)(ws + off);  off += NPASS * PSTRIDE * 4;            // 6,336
    unsigned* cursors = (unsigned*)(ws + off); off += NPASS * PSTRIDE * 4;            // 6,336
    // total: 23,087,232 bytes

    // zero counts + accum (contiguous 5,888 B)
    hipMemsetAsync(counts, 0, NB * NR * NSTRIP * 4 + 256, stream);

    cm_prep<<<NB * NN / 1024, 1024, 0, stream>>>(events, flow, rec, tspol, counts);

    cm_prefix<<<1, 256, 0, stream>>>(counts, starts, cursors);

    for (int p = 0; p < NPASS; ++p) {
        int b = p / 3;
        int pr = p % 3;
        int rbase = pr * 4;
        int nrh = (pr == 2) ? 3 : 4;
        cm_fill<<<NN / 1024, 512, 0, stream>>>(rec, tspol, bins,
                                               cursors + p * PSTRIDE, b, rbase, nrh);
        cm_scan<<<nrh * NSTRIP, 512, 0, stream>>>(bins, starts + p * PSTRIDE,
                                                  b, rbase, accum);
    }

    cm_final<<<1, 64, 0, stream>>>(accum, (float*)d_out);
}